// Round 1
// baseline (524.444 us; speedup 1.0000x reference)
//
#include <hip/hip_runtime.h>
#include <stdint.h>

typedef unsigned short u16;
typedef __attribute__((ext_vector_type(8))) short short8;
typedef __attribute__((ext_vector_type(4))) float floatx4;
typedef __attribute__((ext_vector_type(4))) unsigned short ushort4v;

#define MFMA16(a, b, c) __builtin_amdgcn_mfma_f32_16x16x32_bf16(a, b, c, 0, 0, 0)

// ---- problem constants ----
constexpr int B_ = 4, N_ = 2048, C_ = 1024, H_ = 16, HD = 64;
constexpr size_t SZ_X = (size_t)B_ * N_ * C_;       // 8388608
constexpr size_t SZ_WQKV = (size_t)3 * C_ * C_;     // 3145728
constexpr size_t SZ_WPROJ = (size_t)C_ * C_;        // 1048576
constexpr size_t SZ_QKV = (size_t)B_ * H_ * N_ * HD; // 8388608 per tensor

__device__ __forceinline__ u16 f2bf(float f) {
  union { float f; uint32_t u; } c; c.f = f;
  uint32_t u = c.u;
  return (u16)((u + 0x7FFFu + ((u >> 16) & 1u)) >> 16);  // RNE
}
__device__ __forceinline__ float bf2f(u16 h) {
  union { uint32_t u; float f; } c; c.u = ((uint32_t)h) << 16;
  return c.f;
}
// async global->LDS, 16B per lane; LDS dest = wave-uniform base + lane*16
__device__ __forceinline__ void async16(const u16* g, u16* l) {
  __builtin_amdgcn_global_load_lds(
      (const __attribute__((address_space(1))) void*)g,
      (__attribute__((address_space(3))) void*)l, 16, 0, 0);
}

// ---------------- fp32 -> bf16 cast ----------------
__global__ __launch_bounds__(256) void cvt_bf16(const float* __restrict__ in,
                                                u16* __restrict__ out, int n4) {
  int i = blockIdx.x * 256 + threadIdx.x;
  if (i >= n4) return;
  float4 v = ((const float4*)in)[i];
  ushort4v o;
  o.x = f2bf(v.x); o.y = f2bf(v.y); o.z = f2bf(v.z); o.w = f2bf(v.w);
  ((ushort4v*)out)[i] = o;
}

// ---------------- GEMM: C[m,n] = sum_k A[m,k]*B[n,k] ----------------
// 128x128 tile, BK=32, 4 waves (each 64x64), 16x16x32 bf16 MFMA.
// MODE 0: scatter epilogue -> qb/kb [b,h,n,e], vtb [b,h,e,n] (bf16)
// MODE 1: outf[m*N+n] = acc + bias[n] (fp32)
template <int MODE>
__global__ __launch_bounds__(256) void gemm_bt(
    const u16* __restrict__ A, const u16* __restrict__ Bm, int K,
    u16* __restrict__ qb, u16* __restrict__ kb, u16* __restrict__ vtb,
    float* __restrict__ outf, const float* __restrict__ bias, int N) {
  const int tid = threadIdx.x;
  const int wave = tid >> 6;
  const int lane = tid & 63;
  const int quad = lane >> 4;
  const int l16 = lane & 15;
  const int bm0 = blockIdx.x * 128;
  const int bn0 = blockIdx.y * 128;
  const int wm = (wave >> 1) * 64;
  const int wn = (wave & 1) * 64;

  __shared__ __align__(16) u16 As[128 * 32];
  __shared__ __align__(16) u16 Bs[128 * 32];

  floatx4 acc[4][4];
#pragma unroll
  for (int i = 0; i < 4; ++i)
#pragma unroll
    for (int j = 0; j < 4; ++j)
#pragma unroll
      for (int r = 0; r < 4; ++r) acc[i][j][r] = 0.f;

  for (int k0 = 0; k0 < K; k0 += 32) {
    __syncthreads();  // previous iter's LDS reads done before overwrite
#pragma unroll
    for (int j = 0; j < 2; ++j) {
      const int seg = tid + j * 256;       // 512 segs of 16B per tile
      const int row = seg >> 2;
      const int ks = (seg & 3) * 8;
      u16* la = As + (size_t)(wave * 64 + j * 256) * 8;  // wave-uniform base
      u16* lb = Bs + (size_t)(wave * 64 + j * 256) * 8;
      async16(A + (size_t)(bm0 + row) * K + k0 + ks, la);
      async16(Bm + (size_t)(bn0 + row) * K + k0 + ks, lb);
    }
    __syncthreads();  // barrier drains vmcnt -> tiles visible

    short8 af[4], bf[4];
#pragma unroll
    for (int t = 0; t < 4; ++t)
      af[t] = *(const short8*)(As + (wm + t * 16 + l16) * 32 + quad * 8);
#pragma unroll
    for (int t = 0; t < 4; ++t)
      bf[t] = *(const short8*)(Bs + (wn + t * 16 + l16) * 32 + quad * 8);
#pragma unroll
    for (int i = 0; i < 4; ++i)
#pragma unroll
      for (int j = 0; j < 4; ++j)
        acc[i][j] = MFMA16(af[i], bf[j], acc[i][j]);
  }

  // C/D layout: row = quad*4 + r, col = l16 (per 16x16 tile)
  if (MODE == 0) {
#pragma unroll
    for (int i = 0; i < 4; ++i)
#pragma unroll
      for (int j = 0; j < 4; ++j)
#pragma unroll
        for (int r = 0; r < 4; ++r) {
          const int m = bm0 + wm + i * 16 + quad * 4 + r;  // token
          const int n = bn0 + wn + j * 16 + l16;           // d in [0,3072)
          const u16 bv = f2bf(acc[i][j][r]);
          const int t = n >> 10;
          const int h = (n >> 6) & 15;
          const int e = n & 63;
          const int b = m >> 11;
          const int tok = m & 2047;
          const size_t bh = (size_t)(b * 16 + h);
          if (t == 0)      qb[(bh * 2048 + tok) * 64 + e] = bv;
          else if (t == 1) kb[(bh * 2048 + tok) * 64 + e] = bv;
          else             vtb[(bh * 64 + e) * 2048 + tok] = bv;  // transposed V
        }
  } else {
#pragma unroll
    for (int i = 0; i < 4; ++i)
#pragma unroll
      for (int j = 0; j < 4; ++j)
#pragma unroll
        for (int r = 0; r < 4; ++r) {
          const int m = bm0 + wm + i * 16 + quad * 4 + r;
          const int n = bn0 + wn + j * 16 + l16;
          outf[(size_t)m * N + n] = acc[i][j][r] + bias[n];
        }
  }
}

// ---------------- RMSNorm + RoPE, one wave per 64-elem row ----------------
__global__ __launch_bounds__(256) void normrope(
    u16* __restrict__ qb, u16* __restrict__ kb,
    const float* __restrict__ cosp, const float* __restrict__ sinp,
    const float* __restrict__ qw, const float* __restrict__ kw) {
  const int lane = threadIdx.x & 63;
  const int gid = blockIdx.x * 4 + (threadIdx.x >> 6);  // row over q then k
  const int BHN = B_ * H_ * N_;                          // 131072
  const bool isq = gid < BHN;
  const int rid = isq ? gid : gid - BHN;
  u16* buf = isq ? qb : kb;
  const float* w = isq ? qw : kw;
  const int n = rid & (N_ - 1);  // rid = (b*H+h)*N + n
  const size_t base = (size_t)rid * 64;

  float v = bf2f(buf[base + lane]);
  float ss = v * v;
#pragma unroll
  for (int d = 1; d < 64; d <<= 1) ss += __shfl_xor(ss, d);
  const float inv = 1.0f / sqrtf(ss * (1.0f / 64.0f) + 1e-6f);
  const float xn = v * inv * w[lane];
  const float p = __shfl_xor(xn, 32);
  const float rot = (lane < 32) ? -p : p;  // rotate_half
  const float o = xn * cosp[n * 64 + lane] + rot * sinp[n * 64 + lane];
  buf[base + lane] = f2bf(o);
}

// ---------------- Flash attention: 64-row Q tile per block ----------------
__global__ __launch_bounds__(256) void attn_kernel(
    const u16* __restrict__ qb, const u16* __restrict__ kb,
    const u16* __restrict__ vtb, u16* __restrict__ ob) {
  const int tid = threadIdx.x;
  const int wave = tid >> 6, lane = tid & 63;
  const int quad = lane >> 4, l16 = lane & 15;
  const int bh = blockIdx.y;
  const int q0 = blockIdx.x * 64;

  __shared__ __align__(16) u16 Ks[64 * 64];      // [n][e]
  __shared__ __align__(16) u16 Vs[64 * 64];      // [e][n] (pre-transposed in global)
  __shared__ __align__(16) u16 Ps[4][16 * 72];   // per-wave P, stride 72 = no conflicts

  const u16* qptr = qb + (size_t)bh * (2048 * 64);
  const u16* kptr = kb + (size_t)bh * (2048 * 64);
  const u16* vptr = vtb + (size_t)bh * (64 * 2048);

  // Q fragments (A-layout: m = l16, k = quad*8+j), reused all iterations
  const int qrow = q0 + wave * 16 + l16;
  const short8 aq0 = *(const short8*)(qptr + (size_t)qrow * 64 + quad * 8);
  const short8 aq1 = *(const short8*)(qptr + (size_t)qrow * 64 + 32 + quad * 8);

  floatx4 o[4];
  float mrow[4], lrow[4];
#pragma unroll
  for (int r = 0; r < 4; ++r) { mrow[r] = -3.0e38f; lrow[r] = 0.f; }
#pragma unroll
  for (int et = 0; et < 4; ++et)
#pragma unroll
    for (int r = 0; r < 4; ++r) o[et][r] = 0.f;

  for (int n0 = 0; n0 < 2048; n0 += 64) {
    __syncthreads();  // prior iter's LDS reads done
#pragma unroll
    for (int j = 0; j < 2; ++j) {
      const int seg = j * 256 + tid;
      // K tile: contiguous 8KB
      async16(kptr + (size_t)n0 * 64 + (size_t)seg * 8,
              Ks + (size_t)(j * 256 + wave * 64) * 8);
      // V tile: rows e, 128B each, stride 2048 shorts
      const int e = seg >> 3, part = seg & 7;
      async16(vptr + (size_t)e * 2048 + n0 + part * 8,
              Vs + (size_t)(j * 256 + wave * 64) * 8);
    }
    __syncthreads();  // drain global_load_lds

    // S = scale * Q K^T  (wave: 16 q-rows x 64 keys)
    floatx4 sc[4];
#pragma unroll
    for (int ct = 0; ct < 4; ++ct) {
#pragma unroll
      for (int r = 0; r < 4; ++r) sc[ct][r] = 0.f;
      const short8 b0 = *(const short8*)(Ks + (ct * 16 + l16) * 64 + quad * 8);
      const short8 b1 = *(const short8*)(Ks + (ct * 16 + l16) * 64 + 32 + quad * 8);
      sc[ct] = MFMA16(aq0, b0, sc[ct]);
      sc[ct] = MFMA16(aq1, b1, sc[ct]);
    }

    // online softmax per q-row (row = quad*4 + r)
    float alpha[4];
#pragma unroll
    for (int r = 0; r < 4; ++r) {
      float s0 = sc[0][r] * 0.125f, s1 = sc[1][r] * 0.125f;
      float s2 = sc[2][r] * 0.125f, s3 = sc[3][r] * 0.125f;
      sc[0][r] = s0; sc[1][r] = s1; sc[2][r] = s2; sc[3][r] = s3;
      float mx = fmaxf(fmaxf(s0, s1), fmaxf(s2, s3));
      mx = fmaxf(mx, __shfl_xor(mx, 1));
      mx = fmaxf(mx, __shfl_xor(mx, 2));
      mx = fmaxf(mx, __shfl_xor(mx, 4));
      mx = fmaxf(mx, __shfl_xor(mx, 8));
      const float mnew = fmaxf(mrow[r], mx);
      alpha[r] = __expf(mrow[r] - mnew);
      mrow[r] = mnew;
      float ps = 0.f;
#pragma unroll
      for (int ct = 0; ct < 4; ++ct) {
        const float p = __expf(sc[ct][r] - mnew);
        sc[ct][r] = p;
        ps += p;
      }
      ps += __shfl_xor(ps, 1);
      ps += __shfl_xor(ps, 2);
      ps += __shfl_xor(ps, 4);
      ps += __shfl_xor(ps, 8);
      lrow[r] = lrow[r] * alpha[r] + ps;
    }

    // P: C-layout -> LDS -> A-layout (bf16)
#pragma unroll
    for (int ct = 0; ct < 4; ++ct)
#pragma unroll
      for (int r = 0; r < 4; ++r)
        Ps[wave][(quad * 4 + r) * 72 + ct * 16 + l16] = f2bf(sc[ct][r]);

    __syncthreads();

    const short8 pa0 = *(const short8*)(&Ps[wave][l16 * 72 + quad * 8]);
    const short8 pa1 = *(const short8*)(&Ps[wave][l16 * 72 + 32 + quad * 8]);

#pragma unroll
    for (int et = 0; et < 4; ++et)
#pragma unroll
      for (int r = 0; r < 4; ++r) o[et][r] *= alpha[r];

#pragma unroll
    for (int et = 0; et < 4; ++et) {
      const short8 v0 = *(const short8*)(Vs + (et * 16 + l16) * 64 + quad * 8);
      const short8 v1 = *(const short8*)(Vs + (et * 16 + l16) * 64 + 32 + quad * 8);
      o[et] = MFMA16(pa0, v0, o[et]);
      o[et] = MFMA16(pa1, v1, o[et]);
    }
  }

  // epilogue: O / l -> ob[b][n][h*64+e] (bf16)
  const int b = bh >> 4, h = bh & 15;
#pragma unroll
  for (int et = 0; et < 4; ++et)
#pragma unroll
    for (int r = 0; r < 4; ++r) {
      const int row = q0 + wave * 16 + quad * 4 + r;
      const int e = et * 16 + l16;
      const float val = o[et][r] / lrow[r];
      ob[((size_t)b * 2048 + row) * 1024 + h * 64 + e] = f2bf(val);
    }
}

extern "C" void kernel_launch(void* const* d_in, const int* in_sizes, int n_in,
                              void* d_out, int out_size, void* d_ws, size_t ws_size,
                              hipStream_t stream) {
  const float* x     = (const float*)d_in[0];
  const float* cosp  = (const float*)d_in[1];
  const float* sinp  = (const float*)d_in[2];
  const float* wqkv  = (const float*)d_in[3];
  const float* wproj = (const float*)d_in[4];
  const float* bias  = (const float*)d_in[5];
  const float* qw    = (const float*)d_in[6];
  const float* kw    = (const float*)d_in[7];
  float* out = (float*)d_out;

  // workspace layout (u16), total ~88 MB
  u16* xb     = (u16*)d_ws;
  u16* wqkvb  = xb + SZ_X;
  u16* wprojb = wqkvb + SZ_WQKV;
  u16* qb     = wprojb + SZ_WPROJ;
  u16* kb     = qb + SZ_QKV;
  u16* vtb    = kb + SZ_QKV;
  u16* ob     = vtb + SZ_QKV;

  cvt_bf16<<<(int)(SZ_X / 4 / 256), 256, 0, stream>>>(x, xb, (int)(SZ_X / 4));
  cvt_bf16<<<(int)(SZ_WQKV / 4 / 256), 256, 0, stream>>>(wqkv, wqkvb, (int)(SZ_WQKV / 4));
  cvt_bf16<<<(int)(SZ_WPROJ / 4 / 256), 256, 0, stream>>>(wproj, wprojb, (int)(SZ_WPROJ / 4));

  gemm_bt<0><<<dim3(64, 24), 256, 0, stream>>>(xb, wqkvb, 1024, qb, kb, vtb,
                                               nullptr, nullptr, 3072);
  normrope<<<(2 * B_ * H_ * N_) / 4, 256, 0, stream>>>(qb, kb, cosp, sinp, qw, kw);
  attn_kernel<<<dim3(32, 64), 256, 0, stream>>>(qb, kb, vtb, ob);
  gemm_bt<1><<<dim3(64, 8), 256, 0, stream>>>(ob, wprojb, 1024, nullptr, nullptr,
                                              nullptr, out, bias, 1024);
}

// Round 2
// 359.407 us; speedup vs baseline: 1.4592x; 1.4592x over previous
//
#include <hip/hip_runtime.h>
#include <stdint.h>
#include <math.h>

typedef unsigned short u16;
typedef __attribute__((ext_vector_type(8))) short short8;
typedef __attribute__((ext_vector_type(4))) float floatx4;
typedef __attribute__((ext_vector_type(4))) unsigned short ushort4v;

#define MFMA16(a, b, c) __builtin_amdgcn_mfma_f32_16x16x32_bf16(a, b, c, 0, 0, 0)

// ---- problem constants ----
constexpr int B_ = 4, N_ = 2048, C_ = 1024, H_ = 16, HD = 64;
constexpr size_t SZ_X = (size_t)B_ * N_ * C_;       // 8388608
constexpr size_t SZ_WQKV = (size_t)3 * C_ * C_;     // 3145728
constexpr size_t SZ_WPROJ = (size_t)C_ * C_;        // 1048576
constexpr size_t SZ_QKV = (size_t)B_ * H_ * N_ * HD; // 8388608 per tensor

// softmax scale (1/sqrt(64)) * log2(e), folded into q so scores are exp2-ready
#define QSCALE 0.1803368801111204f

__device__ __forceinline__ u16 f2bf(float f) {
  union { float f; uint32_t u; } c; c.f = f;
  uint32_t u = c.u;
  return (u16)((u + 0x7FFFu + ((u >> 16) & 1u)) >> 16);  // RNE
}
// cheap round-half-up (values here are finite, no NaN): 2 VALU ops
__device__ __forceinline__ u16 f2bf_fast(float f) {
  union { float f; uint32_t u; } c; c.f = f;
  return (u16)((c.u + 0x8000u) >> 16);
}
__device__ __forceinline__ float bf2f(u16 h) {
  union { uint32_t u; float f; } c; c.u = ((uint32_t)h) << 16;
  return c.f;
}
// async global->LDS, 16B per lane; LDS dest = wave-uniform base + lane*16
__device__ __forceinline__ void async16(const u16* g, u16* l) {
  __builtin_amdgcn_global_load_lds(
      (const __attribute__((address_space(1))) void*)g,
      (__attribute__((address_space(3))) void*)l, 16, 0, 0);
}

// ---------------- fp32 -> bf16 cast ----------------
__global__ __launch_bounds__(256) void cvt_bf16(const float* __restrict__ in,
                                                u16* __restrict__ out, int n4) {
  int i = blockIdx.x * 256 + threadIdx.x;
  if (i >= n4) return;
  float4 v = ((const float4*)in)[i];
  ushort4v o;
  o.x = f2bf(v.x); o.y = f2bf(v.y); o.z = f2bf(v.z); o.w = f2bf(v.w);
  ((ushort4v*)out)[i] = o;
}

// ---------------- GEMM: C[m,n] = sum_k A[m,k]*B[n,k] ----------------
// 128x128 tile, BK=32, 4 waves (each 64x64), 16x16x32 bf16 MFMA.
// MODE 0: scatter epilogue -> qb/kb [b,h,n,e], vtb [b,h,e,n] (bf16)
// MODE 1: outf[m*N+n] = acc + bias[n] (fp32)
template <int MODE>
__global__ __launch_bounds__(256) void gemm_bt(
    const u16* __restrict__ A, const u16* __restrict__ Bm, int K,
    u16* __restrict__ qb, u16* __restrict__ kb, u16* __restrict__ vtb,
    float* __restrict__ outf, const float* __restrict__ bias, int N) {
  const int tid = threadIdx.x;
  const int wave = tid >> 6;
  const int lane = tid & 63;
  const int quad = lane >> 4;
  const int l16 = lane & 15;
  const int bm0 = blockIdx.x * 128;
  const int bn0 = blockIdx.y * 128;
  const int wm = (wave >> 1) * 64;
  const int wn = (wave & 1) * 64;

  __shared__ __align__(16) u16 As[128 * 32];
  __shared__ __align__(16) u16 Bs[128 * 32];

  floatx4 acc[4][4];
#pragma unroll
  for (int i = 0; i < 4; ++i)
#pragma unroll
    for (int j = 0; j < 4; ++j)
#pragma unroll
      for (int r = 0; r < 4; ++r) acc[i][j][r] = 0.f;

  for (int k0 = 0; k0 < K; k0 += 32) {
    __syncthreads();  // previous iter's LDS reads done before overwrite
#pragma unroll
    for (int j = 0; j < 2; ++j) {
      const int seg = tid + j * 256;       // 512 segs of 16B per tile
      const int row = seg >> 2;
      const int ks = (seg & 3) * 8;
      u16* la = As + (size_t)(wave * 64 + j * 256) * 8;  // wave-uniform base
      u16* lb = Bs + (size_t)(wave * 64 + j * 256) * 8;
      async16(A + (size_t)(bm0 + row) * K + k0 + ks, la);
      async16(Bm + (size_t)(bn0 + row) * K + k0 + ks, lb);
    }
    __syncthreads();  // barrier drains vmcnt -> tiles visible

    short8 af[4], bf[4];
#pragma unroll
    for (int t = 0; t < 4; ++t)
      af[t] = *(const short8*)(As + (wm + t * 16 + l16) * 32 + quad * 8);
#pragma unroll
    for (int t = 0; t < 4; ++t)
      bf[t] = *(const short8*)(Bs + (wn + t * 16 + l16) * 32 + quad * 8);
#pragma unroll
    for (int i = 0; i < 4; ++i)
#pragma unroll
      for (int j = 0; j < 4; ++j)
        acc[i][j] = MFMA16(af[i], bf[j], acc[i][j]);
  }

  // C/D layout: row = quad*4 + r, col = l16 (per 16x16 tile)
  if (MODE == 0) {
#pragma unroll
    for (int i = 0; i < 4; ++i)
#pragma unroll
      for (int j = 0; j < 4; ++j)
#pragma unroll
        for (int r = 0; r < 4; ++r) {
          const int m = bm0 + wm + i * 16 + quad * 4 + r;  // token
          const int n = bn0 + wn + j * 16 + l16;           // d in [0,3072)
          const u16 bv = f2bf(acc[i][j][r]);
          const int t = n >> 10;
          const int h = (n >> 6) & 15;
          const int e = n & 63;
          const int b = m >> 11;
          const int tok = m & 2047;
          const size_t bh = (size_t)(b * 16 + h);
          if (t == 0)      qb[(bh * 2048 + tok) * 64 + e] = bv;
          else if (t == 1) kb[(bh * 2048 + tok) * 64 + e] = bv;
          else             vtb[(bh * 64 + e) * 2048 + tok] = bv;  // transposed V
        }
  } else {
#pragma unroll
    for (int i = 0; i < 4; ++i)
#pragma unroll
      for (int j = 0; j < 4; ++j)
#pragma unroll
        for (int r = 0; r < 4; ++r) {
          const int m = bm0 + wm + i * 16 + quad * 4 + r;
          const int n = bn0 + wn + j * 16 + l16;
          outf[(size_t)m * N + n] = acc[i][j][r] + bias[n];
        }
  }
}

// ---------------- RMSNorm + RoPE, one wave per 64-elem row ----------------
// q additionally scaled by QSCALE so attention scores feed exp2 directly.
__global__ __launch_bounds__(256) void normrope(
    u16* __restrict__ qb, u16* __restrict__ kb,
    const float* __restrict__ cosp, const float* __restrict__ sinp,
    const float* __restrict__ qw, const float* __restrict__ kw) {
  const int lane = threadIdx.x & 63;
  const int gid = blockIdx.x * 4 + (threadIdx.x >> 6);  // row over q then k
  const int BHN = B_ * H_ * N_;                          // 131072
  const bool isq = gid < BHN;
  const int rid = isq ? gid : gid - BHN;
  u16* buf = isq ? qb : kb;
  const float* w = isq ? qw : kw;
  const int n = rid & (N_ - 1);  // rid = (b*H+h)*N + n
  const size_t base = (size_t)rid * 64;

  float v = bf2f(buf[base + lane]);
  float ss = v * v;
#pragma unroll
  for (int d = 1; d < 64; d <<= 1) ss += __shfl_xor(ss, d);
  const float inv = 1.0f / sqrtf(ss * (1.0f / 64.0f) + 1e-6f);
  const float xn = v * inv * w[lane];
  const float p = __shfl_xor(xn, 32);
  const float rot = (lane < 32) ? -p : p;  // rotate_half
  float o = xn * cosp[n * 64 + lane] + rot * sinp[n * 64 + lane];
  if (isq) o *= QSCALE;
  buf[base + lane] = f2bf(o);
}

// ---------------- Flash attention: 128-row Q tile per block ----------------
// K/V tiles staged in MFMA-FRAGMENT ORDER (conflict-free ds_read_b128),
// fixed-max softmax (scores bounded), l via MFMA against all-ones B fragment.
__global__ __launch_bounds__(256, 4) void attn_kernel(
    const u16* __restrict__ qb, const u16* __restrict__ kb,
    const u16* __restrict__ vtb, u16* __restrict__ ob) {
  const int tid = threadIdx.x;
  const int wave = tid >> 6, lane = tid & 63;
  const int quad = lane >> 4, l16 = lane & 15;
  const int bh = blockIdx.y;
  const int q0 = blockIdx.x * 128;

  // fragment-order tiles: u16 index = seg*8, seg = ct*128 + half*64 + lane
  __shared__ __align__(16) u16 Ksf[64 * 64];         // K tile, fragment order
  __shared__ __align__(16) u16 Vsf[64 * 64];         // V^T tile, fragment order
  __shared__ __align__(16) u16 Ps[4][2][16 * 72];    // per-wave, per-sub P

  const u16* qptr = qb + (size_t)bh * (2048 * 64);
  const u16* kptr = kb + (size_t)bh * (2048 * 64);
  const u16* vptr = vtb + (size_t)bh * (64 * 2048);

  // staging addresses (loop-invariant parts)
  const int s0 = tid, s1 = tid + 256;
  const int ct0 = s0 >> 7, ct1 = s1 >> 7;
  const int hf0 = (s0 >> 6) & 1, hf1 = (s1 >> 6) & 1;
  const u16* kg0 = kptr + (size_t)(ct0 * 16 + l16) * 64 + hf0 * 32 + quad * 8;
  const u16* kg1 = kptr + (size_t)(ct1 * 16 + l16) * 64 + hf1 * 32 + quad * 8;
  const u16* vg0 = vptr + (size_t)(ct0 * 16 + l16) * 2048 + hf0 * 32 + quad * 8;
  const u16* vg1 = vptr + (size_t)(ct1 * 16 + l16) * 2048 + hf1 * 32 + quad * 8;
  u16* kl0 = Ksf + (size_t)(wave * 64) * 8;
  u16* kl1 = Ksf + (size_t)(256 + wave * 64) * 8;
  u16* vl0 = Vsf + (size_t)(wave * 64) * 8;
  u16* vl1 = Vsf + (size_t)(256 + wave * 64) * 8;

  // Q fragments: 2 q-subtiles of 16 rows each (A-layout: m=l16, k=quad*8+j)
  short8 aq[2][2];
#pragma unroll
  for (int sub = 0; sub < 2; ++sub) {
    const int qrow = q0 + wave * 32 + sub * 16 + l16;
#pragma unroll
    for (int hf = 0; hf < 2; ++hf)
      aq[sub][hf] =
          *(const short8*)(qptr + (size_t)qrow * 64 + hf * 32 + quad * 8);
  }

  // all-ones bf16 B fragment for the l = P*1 row-sum MFMA
  short8 ones;
#pragma unroll
  for (int j = 0; j < 8; ++j) ones[j] = (short)0x3F80;

  floatx4 o[2][4], ol[2];
#pragma unroll
  for (int sub = 0; sub < 2; ++sub) {
#pragma unroll
    for (int r = 0; r < 4; ++r) ol[sub][r] = 0.f;
#pragma unroll
    for (int et = 0; et < 4; ++et)
#pragma unroll
      for (int r = 0; r < 4; ++r) o[sub][et][r] = 0.f;
  }

  for (int n0 = 0; n0 < 2048; n0 += 64) {
    __syncthreads();  // all waves done reading Ksf/Vsf from previous iter
    async16(kg0 + (size_t)n0 * 64, kl0);
    async16(kg1 + (size_t)n0 * 64, kl1);
    async16(vg0 + n0, vl0);
    async16(vg1 + n0, vl1);
    __syncthreads();  // drains vmcnt -> tiles visible

    // S' = (q*scale*log2e) . K   (both subs share each K fragment)
    floatx4 sc[2][4];
#pragma unroll
    for (int ct = 0; ct < 4; ++ct) {
      const short8 kb0 = *(const short8*)(Ksf + ct * 1024 + lane * 8);
      const short8 kb1 = *(const short8*)(Ksf + ct * 1024 + 512 + lane * 8);
#pragma unroll
      for (int sub = 0; sub < 2; ++sub) {
        floatx4 z;
#pragma unroll
        for (int r = 0; r < 4; ++r) z[r] = 0.f;
        z = MFMA16(aq[sub][0], kb0, z);
        sc[sub][ct] = MFMA16(aq[sub][1], kb1, z);
      }
    }

    // p = 2^s (no max subtraction; scores bounded), write P in bf16
#pragma unroll
    for (int sub = 0; sub < 2; ++sub)
#pragma unroll
      for (int ct = 0; ct < 4; ++ct)
#pragma unroll
        for (int r = 0; r < 4; ++r) {
          const float p = exp2f(sc[sub][ct][r]);
          Ps[wave][sub][(quad * 4 + r) * 72 + ct * 16 + l16] = f2bf_fast(p);
        }

    // same-wave DS ordering: drain writes before fragment reads
    __asm__ volatile("s_waitcnt lgkmcnt(0)" ::: "memory");

    short8 pa[2][2];
#pragma unroll
    for (int sub = 0; sub < 2; ++sub) {
      pa[sub][0] = *(const short8*)(&Ps[wave][sub][l16 * 72 + quad * 8]);
      pa[sub][1] = *(const short8*)(&Ps[wave][sub][l16 * 72 + 32 + quad * 8]);
    }

    // O += P . V ; l += P . 1
#pragma unroll
    for (int et = 0; et < 4; ++et) {
      const short8 vb0 = *(const short8*)(Vsf + et * 1024 + lane * 8);
      const short8 vb1 = *(const short8*)(Vsf + et * 1024 + 512 + lane * 8);
#pragma unroll
      for (int sub = 0; sub < 2; ++sub) {
        o[sub][et] = MFMA16(pa[sub][0], vb0, o[sub][et]);
        o[sub][et] = MFMA16(pa[sub][1], vb1, o[sub][et]);
      }
    }
#pragma unroll
    for (int sub = 0; sub < 2; ++sub) {
      ol[sub] = MFMA16(pa[sub][0], ones, ol[sub]);
      ol[sub] = MFMA16(pa[sub][1], ones, ol[sub]);
    }
  }

  // epilogue: O / l -> ob[b][n][h*64+e] (bf16)
  const int b = bh >> 4, h = bh & 15;
#pragma unroll
  for (int sub = 0; sub < 2; ++sub) {
    float inv[4];
#pragma unroll
    for (int r = 0; r < 4; ++r) inv[r] = 1.0f / ol[sub][r];
#pragma unroll
    for (int et = 0; et < 4; ++et)
#pragma unroll
      for (int r = 0; r < 4; ++r) {
        const int row = q0 + wave * 32 + sub * 16 + quad * 4 + r;
        const int e = et * 16 + l16;
        ob[((size_t)b * 2048 + row) * 1024 + h * 64 + e] =
            f2bf(o[sub][et][r] * inv[r]);
      }
  }
}

extern "C" void kernel_launch(void* const* d_in, const int* in_sizes, int n_in,
                              void* d_out, int out_size, void* d_ws, size_t ws_size,
                              hipStream_t stream) {
  const float* x     = (const float*)d_in[0];
  const float* cosp  = (const float*)d_in[1];
  const float* sinp  = (const float*)d_in[2];
  const float* wqkv  = (const float*)d_in[3];
  const float* wproj = (const float*)d_in[4];
  const float* bias  = (const float*)d_in[5];
  const float* qw    = (const float*)d_in[6];
  const float* kw    = (const float*)d_in[7];
  float* out = (float*)d_out;

  // workspace layout (u16), total ~88 MB
  u16* xb     = (u16*)d_ws;
  u16* wqkvb  = xb + SZ_X;
  u16* wprojb = wqkvb + SZ_WQKV;
  u16* qb     = wprojb + SZ_WPROJ;
  u16* kb     = qb + SZ_QKV;
  u16* vtb    = kb + SZ_QKV;
  u16* ob     = vtb + SZ_QKV;

  cvt_bf16<<<(int)(SZ_X / 4 / 256), 256, 0, stream>>>(x, xb, (int)(SZ_X / 4));
  cvt_bf16<<<(int)(SZ_WQKV / 4 / 256), 256, 0, stream>>>(wqkv, wqkvb, (int)(SZ_WQKV / 4));
  cvt_bf16<<<(int)(SZ_WPROJ / 4 / 256), 256, 0, stream>>>(wproj, wprojb, (int)(SZ_WPROJ / 4));

  gemm_bt<0><<<dim3(64, 24), 256, 0, stream>>>(xb, wqkvb, 1024, qb, kb, vtb,
                                               nullptr, nullptr, 3072);
  normrope<<<(2 * B_ * H_ * N_) / 4, 256, 0, stream>>>(qb, kb, cosp, sinp, qw, kw);
  attn_kernel<<<dim3(16, 64), 256, 0, stream>>>(qb, kb, vtb, ob);
  gemm_bt<1><<<dim3(64, 8), 256, 0, stream>>>(ob, wprojb, 1024, nullptr, nullptr,
                                              nullptr, out, bias, 1024);
}